// Round 2
// baseline (621.386 us; speedup 1.0000x reference)
//
#include <hip/hip_runtime.h>
#include <hip/hip_bf16.h>
#include <cstdint>
#include <cstddef>

// Grouped MoE FFN: h = gelu(x @ w1[e]^T + b1[e]); out = h @ w2[e]^T + b2[e]
// ALL INPUTS ARE FP32.
// R5 change: eliminate w1/w2 pre-convert dispatches (they cost ~110us and
// cancelled the R4 GEMM win). B (weights) now staged as RAW FP32 via
// global_load_lds into a swizzled [128][32]f32 LDS tile; fp32->bf16 convert
// happens at fragment-read (2x ds_read_b128 + 8 scalar cvt -> compiler emits
// v_cvt_pk_bf16_f32, m240). A stays bf16 (cheap x-convert; h produced bf16).
// fp32 tile has 128B rows => 16-way bank conflict if linear; fixed per rule
// #21: pre-swizzled GLOBAL source (col = 4*((lane&7)^(row&7))) + XOR on read
// (byte ^= (row&7)<<4) -- same involution both sides, global_load_lds dest
// stays linear.

using bf16 = __hip_bfloat16;
typedef __attribute__((ext_vector_type(8))) short bf16x8;   // 8 bf16 = 4 VGPRs
typedef __attribute__((ext_vector_type(4))) float f32x4;

#define BM 128
#define BN 128
#define BK 32

typedef const __attribute__((address_space(1))) unsigned int g_u32;
typedef __attribute__((address_space(3))) unsigned int l_u32;

// async global->LDS, 16 bytes per lane. LDS dest = wave-uniform base + lane*16.
__device__ __forceinline__ void async16(void* lds, const void* g) {
  __builtin_amdgcn_global_load_lds((g_u32*)g, (l_u32*)lds, 16, 0, 0);
}

__device__ __forceinline__ float gelu_f(float x) {
  // tanh-approx gelu (jax.nn.gelu default approximate=True)
  const float c0 = 0.7978845608028654f;  // sqrt(2/pi)
  const float c1 = 0.044715f;
  float u = c0 * (x + c1 * x * x * x);
  float t = 1.0f - 2.0f / (__expf(2.0f * u) + 1.0f);
  return 0.5f * x * (1.0f + t);
}

// ---------------- fp32 -> bf16 streaming convert (x only, ~8us) ------------
__global__ __launch_bounds__(256) void f32_to_bf16(
    const float* __restrict__ in, bf16* __restrict__ out, size_t n) {
  size_t i = ((size_t)blockIdx.x * blockDim.x + threadIdx.x) * 8;
  const size_t stride = (size_t)gridDim.x * blockDim.x * 8;
  for (; i < n; i += stride) {
    f32x4 lo = *(const f32x4*)(in + i);
    f32x4 hi = *(const f32x4*)(in + i + 4);
    bf16 cv[8];
#pragma unroll
    for (int k = 0; k < 4; ++k) {
      cv[k]     = __float2bfloat16(lo[k]);
      cv[k + 4] = __float2bfloat16(hi[k]);
    }
    *(bf16x8*)(out + i) = *(const bf16x8*)cv;
  }
}

// ---------- fast path: A bf16 (global_load_lds), B fp32 (global_load_lds,
// ---------- swizzled source, fragment-time convert) -------------------------
__global__ __launch_bounds__(256) void gemm_bt_a16_b32(
    const bf16* __restrict__ A,      // [M, K] row-major bf16
    const float* __restrict__ B,     // [E, N, K] row-major FP32 (B^T gemm)
    const float* __restrict__ bias,  // [E, N] fp32
    void* __restrict__ Cv,           // [M, N] output
    const int* __restrict__ counts,  // [E]
    int E, int N, int K, int c_is_bf16_gelu)
{
  __shared__ alignas(16) bf16  As[BM * BK];   // 8 KB, linear
  __shared__ alignas(16) float BsF[BN * BK];  // 16 KB, XOR-swizzled rows

  const int tid  = threadIdx.x;
  const int lane = tid & 63;
  const int wave = tid >> 6;
  const int m0 = blockIdx.y * BM;
  const int n0 = blockIdx.x * BN;

  // expert id for this row tile; block-uniform (no divergent barriers)
  int eid = 0;
  {
    long long cum = 0;
    for (int e = 0; e < E; ++e) { cum += counts[e]; if (m0 >= cum) eid = e + 1; }
  }

  const int wrow = (wave >> 1) * 64;   // wave tile 64x64 within 128x128
  const int wcol = (wave & 1) * 64;

  f32x4 acc[4][4] = {};

  if (eid < E) {
    const float* Bexp = B + (size_t)eid * (size_t)N * (size_t)K;

    // --- A staging: 128x32 bf16 = 8KB = 8 chunks of 1024B (16 rows each).
    // Wave w stages chunks {2w, 2w+1}; lane l -> row l>>2, colseg (l&3)*8.
    const int rA = lane >> 2;
    const int sA = (lane & 3) * 8;

    // --- B staging: 128x32 fp32 = 16KB = 16 chunks of 1024B (8 rows each).
    // Wave w stages chunks {4w..4w+3}; lane l -> row_in_chunk l>>3.
    // Pre-swizzled source col (floats): 4*((l&7)^(row&7)); (row&7)=(l>>3)&7
    // is chunk-invariant, so col is a per-lane constant.
    const int rB   = lane >> 3;                       // row within 8-row chunk
    const int colB = 4 * ((lane & 7) ^ (rB & 7));     // swizzled float col

    const int frow = lane & 15;        // A/B frag row (m or n within 16)
    const int fk   = (lane >> 4) * 8;  // A/B frag k-offset (quad*8)
    const int fkb  = fk * 4;           // frag k byte offset in fp32 row (0..96)

    for (int kt = 0; kt < K; kt += BK) {
#pragma unroll
      for (int c = 0; c < 2; ++c) {
        const int chunk = wave * 2 + c;
        const int row = chunk * 16 + rA;
        async16(&As[chunk * 16 * BK],
                A + (size_t)(m0 + row) * K + kt + sA);
      }
#pragma unroll
      for (int c = 0; c < 4; ++c) {
        const int chunk = wave * 4 + c;
        const int row = chunk * 8 + rB;
        async16(&BsF[chunk * 256],     // 256 floats = 1024B per chunk
                Bexp + (size_t)(n0 + row) * K + kt + colB);
      }
      __syncthreads();   // includes vmcnt(0): staged tiles visible to all

      bf16x8 af[4], bfr[4];
#pragma unroll
      for (int i = 0; i < 4; ++i)
        af[i] = *(const bf16x8*)&As[(wrow + i * 16 + frow) * BK + fk];
#pragma unroll
      for (int j = 0; j < 4; ++j) {
        const int brow = wcol + j * 16 + frow;
        // swizzled read: byte = brow*128 + (fkb ^ ((brow&7)<<4)); second 16B
        // of the fragment (logical c+16) lands at addr ^ 16 (bit4 of fkb = 0)
        uintptr_t a1 = (uintptr_t)BsF + (uintptr_t)brow * 128
                     + (uintptr_t)(fkb ^ ((brow & 7) << 4));
        f32x4 lo = *(const f32x4*)a1;
        f32x4 hi = *(const f32x4*)(a1 ^ 16);
        bf16 cv[8];
#pragma unroll
        for (int q = 0; q < 4; ++q) {
          cv[q]     = __float2bfloat16(lo[q]);
          cv[q + 4] = __float2bfloat16(hi[q]);
        }
        bfr[j] = *(const bf16x8*)cv;
      }

#pragma unroll
      for (int i = 0; i < 4; ++i)
#pragma unroll
        for (int j = 0; j < 4; ++j)
          acc[i][j] = __builtin_amdgcn_mfma_f32_16x16x32_bf16(af[i], bfr[j], acc[i][j], 0, 0, 0);

      __syncthreads();   // all reads done before next iter's staging writes
    }
  }

  // epilogue: C/D layout col=lane&15, row=(lane>>4)*4+reg (m89-verified)
  const int crow = (lane >> 4) * 4;
  const int ccol = lane & 15;
  const int do_gelu = c_is_bf16_gelu;

  if (eid < E) {
    float bv[4];
#pragma unroll
    for (int j = 0; j < 4; ++j)
      bv[j] = bias[(size_t)eid * N + n0 + wcol + j * 16 + ccol];
#pragma unroll
    for (int i = 0; i < 4; ++i) {
#pragma unroll
      for (int r = 0; r < 4; ++r) {
        size_t grow = (size_t)(m0 + wrow + i * 16 + crow + r);
#pragma unroll
        for (int j = 0; j < 4; ++j) {
          float v = acc[i][j][r] + bv[j];
          size_t idx = grow * N + n0 + wcol + j * 16 + ccol;
          if (do_gelu) ((bf16*)Cv)[idx] = __float2bfloat16(gelu_f(v));
          else         ((float*)Cv)[idx] = v;
        }
      }
    }
  } else {
    // tokens beyond cumsum(counts): write zeros
#pragma unroll
    for (int i = 0; i < 4; ++i) {
#pragma unroll
      for (int r = 0; r < 4; ++r) {
        size_t grow = (size_t)(m0 + wrow + i * 16 + crow + r);
#pragma unroll
        for (int j = 0; j < 4; ++j) {
          size_t idx = grow * N + n0 + wcol + j * 16 + ccol;
          if (do_gelu) ((bf16*)Cv)[idx] = __float2bfloat16(0.0f);
          else         ((float*)Cv)[idx] = 0.0f;
        }
      }
    }
  }
}

// ---------------- fallback path (proven reg-staged kernel) ------------------
__device__ __forceinline__ void stage_f32(const float* g, bf16* lds,
                                          int srow, int seg, int ldg) {
#pragma unroll
  for (int h = 0; h < 2; ++h) {
    const float* p = g + (size_t)(srow + h * 64) * ldg + seg;
    f32x4 lo = *(const f32x4*)(p);
    f32x4 hi = *(const f32x4*)(p + 4);
    bf16 cv[8];
#pragma unroll
    for (int i = 0; i < 4; ++i) {
      cv[i]     = __float2bfloat16(lo[i]);
      cv[i + 4] = __float2bfloat16(hi[i]);
    }
    *(bf16x8*)&lds[(srow + h * 64) * BK + seg] = *(const bf16x8*)cv;
  }
}

__device__ __forceinline__ void stage_bf16(const bf16* g, bf16* lds,
                                           int srow, int seg, int ldg) {
#pragma unroll
  for (int h = 0; h < 2; ++h) {
    const bf16* p = g + (size_t)(srow + h * 64) * ldg + seg;
    *(bf16x8*)&lds[(srow + h * 64) * BK + seg] = *(const bf16x8*)p;
  }
}

template <bool AF32>
__global__ __launch_bounds__(256) void grouped_gemm_bt(
    const void* __restrict__ Av, const float* __restrict__ B,
    const float* __restrict__ bias, void* __restrict__ Cv,
    const int* __restrict__ counts, int E, int N, int K, int c_is_bf16_gelu)
{
  __shared__ alignas(16) bf16 As[BM * BK];
  __shared__ alignas(16) bf16 Bs[BN * BK];

  const int tid  = threadIdx.x;
  const int lane = tid & 63;
  const int wave = tid >> 6;
  const int m0 = blockIdx.y * BM;
  const int n0 = blockIdx.x * BN;

  int eid = 0;
  {
    long long cum = 0;
    for (int e = 0; e < E; ++e) { cum += counts[e]; if (m0 >= cum) eid = e + 1; }
  }

  const int wrow = (wave >> 1) * 64;
  const int wcol = (wave & 1) * 64;

  f32x4 acc[4][4] = {};

  if (eid < E) {
    const float* Bexp = B + (size_t)eid * (size_t)N * (size_t)K;
    const int srow = tid >> 2;
    const int seg  = (tid & 3) * 8;
    const int frow = lane & 15;
    const int fk   = (lane >> 4) * 8;

    for (int kt = 0; kt < K; kt += BK) {
      if (AF32)
        stage_f32((const float*)Av + (size_t)(m0 + srow) * K + kt - (size_t)srow * K,
                  As, srow, seg, K);
      else
        stage_bf16((const bf16*)Av + (size_t)(m0 + srow) * K + kt - (size_t)srow * K,
                   As, srow, seg, K);
      stage_f32(Bexp + (size_t)(n0 + srow) * K + kt - (size_t)srow * K,
                Bs, srow, seg, K);
      __syncthreads();

      bf16x8 af[4], bfr[4];
#pragma unroll
      for (int i = 0; i < 4; ++i)
        af[i] = *(const bf16x8*)&As[(wrow + i * 16 + frow) * BK + fk];
#pragma unroll
      for (int j = 0; j < 4; ++j)
        bfr[j] = *(const bf16x8*)&Bs[(wcol + j * 16 + frow) * BK + fk];

#pragma unroll
      for (int i = 0; i < 4; ++i)
#pragma unroll
        for (int j = 0; j < 4; ++j)
          acc[i][j] = __builtin_amdgcn_mfma_f32_16x16x32_bf16(af[i], bfr[j], acc[i][j], 0, 0, 0);

      __syncthreads();
    }
  }

  const int crow = (lane >> 4) * 4;
  const int ccol = lane & 15;
  const int do_gelu = c_is_bf16_gelu;

  if (eid < E) {
    float bv[4];
#pragma unroll
    for (int j = 0; j < 4; ++j)
      bv[j] = bias[(size_t)eid * N + n0 + wcol + j * 16 + ccol];
#pragma unroll
    for (int i = 0; i < 4; ++i) {
#pragma unroll
      for (int r = 0; r < 4; ++r) {
        size_t grow = (size_t)(m0 + wrow + i * 16 + crow + r);
#pragma unroll
        for (int j = 0; j < 4; ++j) {
          float v = acc[i][j][r] + bv[j];
          size_t idx = grow * N + n0 + wcol + j * 16 + ccol;
          if (do_gelu) ((bf16*)Cv)[idx] = __float2bfloat16(gelu_f(v));
          else         ((float*)Cv)[idx] = v;
        }
      }
    }
  } else {
#pragma unroll
    for (int i = 0; i < 4; ++i) {
#pragma unroll
      for (int r = 0; r < 4; ++r) {
        size_t grow = (size_t)(m0 + wrow + i * 16 + crow + r);
#pragma unroll
        for (int j = 0; j < 4; ++j) {
          size_t idx = grow * N + n0 + wcol + j * 16 + ccol;
          if (do_gelu) ((bf16*)Cv)[idx] = __float2bfloat16(0.0f);
          else         ((float*)Cv)[idx] = 0.0f;
        }
      }
    }
  }
}

extern "C" void kernel_launch(void* const* d_in, const int* in_sizes, int n_in,
                              void* d_out, int out_size, void* d_ws, size_t ws_size,
                              hipStream_t stream) {
  const float* inp = (const float*)d_in[0];  // [T, D] fp32
  const float* w1  = (const float*)d_in[1];  // [E, H, D] fp32
  const float* b1  = (const float*)d_in[2];  // [E, H] fp32
  const float* w2  = (const float*)d_in[3];  // [E, D, H] fp32
  const float* b2  = (const float*)d_in[4];  // [E, D] fp32
  const int* cnt   = (const int*)d_in[5];    // [E] int32
  float* out = (float*)d_out;                // [T, D] fp32

  const int E = in_sizes[5];
  const int H = in_sizes[2] / E;             // b1 = E*H
  const int D = in_sizes[4] / E;             // b2 = E*D
  const int T = in_sizes[0] / D;             // inp = T*D

  const size_t szH = (size_t)T * H * sizeof(bf16);  // h buffer (bf16)
  const size_t szX = (size_t)T * D * sizeof(bf16);  // x bf16

  dim3 blk(256);

  if (ws_size >= szH + szX) {
    // fast path: convert x only (~8us); weights read as raw fp32 by the GEMM.
    bf16* h  = (bf16*)d_ws;                          // [T, H]
    bf16* xb = (bf16*)((char*)d_ws + szH);           // [T, D]

    f32_to_bf16<<<dim3(1024), blk, 0, stream>>>(inp, xb, (size_t)T * D);
    gemm_bt_a16_b32<<<dim3(H / BN, T / BM), blk, 0, stream>>>(
        xb, w1, b1, h, cnt, E, H, D, 1);
    gemm_bt_a16_b32<<<dim3(D / BN, T / BM), blk, 0, stream>>>(
        h, w2, b2, out, cnt, E, D, H, 0);
  } else {
    // fallback: proven reg-staged kernel
    bf16* h = (bf16*)d_ws;                           // [T, H]
    grouped_gemm_bt<true><<<dim3(H / BN, T / BM), blk, 0, stream>>>(inp, w1, b1, h, cnt, E, H, D, 1);
    grouped_gemm_bt<false><<<dim3(D / BN, T / BM), blk, 0, stream>>>(h, w2, b2, out, cnt, E, D, H, 0);
  }
}

// Round 3
// 558.503 us; speedup vs baseline: 1.1126x; 1.1126x over previous
//
#include <hip/hip_runtime.h>
#include <hip/hip_bf16.h>
#include <cstdint>
#include <cstddef>

// Grouped MoE FFN: h = gelu(x @ w1[e]^T + b1[e]); out = h @ w2[e]^T + b2[e]
// ALL INPUTS ARE FP32.
// R6: revert R5's fp32-B staging (regressed: +bank conflicts, +staging bytes).
// Back to R4's all-bf16 global_load_lds GEMM, plus:
//  - T3 minimum 2-phase prefetch: double-buffered LDS, STAGE(next) issued
//    before compute(cur), raw s_barrier + counted s_waitcnt vmcnt(4) (never
//    0 in main loop; drain only in epilogue). m248: 494 -> ~660 TF class.
//  - T1 bijective XCD block swizzle (m204) for A-panel L2 locality.
//  - converts fused: 1 dispatch for x+w1, 1 for w2 (reuses same ws slot,
//    stream-serial after GEMM1). Workspace footprint unchanged (144 MB).

using bf16 = __hip_bfloat16;
typedef __attribute__((ext_vector_type(8))) short bf16x8;   // 8 bf16 = 4 VGPRs
typedef __attribute__((ext_vector_type(4))) float f32x4;

#define BM 128
#define BN 128
#define BK 32

typedef const __attribute__((address_space(1))) unsigned int g_u32;
typedef __attribute__((address_space(3))) unsigned int l_u32;

// async global->LDS, 16 bytes per lane. LDS dest = wave-uniform base + lane*16.
__device__ __forceinline__ void async16(void* lds, const void* g) {
  __builtin_amdgcn_global_load_lds((g_u32*)g, (l_u32*)lds, 16, 0, 0);
}

__device__ __forceinline__ float gelu_f(float x) {
  // tanh-approx gelu (jax.nn.gelu default approximate=True)
  const float c0 = 0.7978845608028654f;  // sqrt(2/pi)
  const float c1 = 0.044715f;
  float u = c0 * (x + c1 * x * x * x);
  float t = 1.0f - 2.0f / (__expf(2.0f * u) + 1.0f);
  return 0.5f * x * (1.0f + t);
}

// ------------- fp32 -> bf16 streaming convert, two arrays per launch --------
__global__ __launch_bounds__(256) void f32_to_bf16_2(
    const float* __restrict__ a, bf16* __restrict__ oa, size_t na,
    const float* __restrict__ b, bf16* __restrict__ ob, size_t nb) {
  const size_t stride = (size_t)gridDim.x * blockDim.x * 8;
  const size_t base = ((size_t)blockIdx.x * blockDim.x + threadIdx.x) * 8;
  for (size_t i = base; i < na; i += stride) {
    f32x4 lo = *(const f32x4*)(a + i);
    f32x4 hi = *(const f32x4*)(a + i + 4);
    bf16 cv[8];
#pragma unroll
    for (int k = 0; k < 4; ++k) {
      cv[k]     = __float2bfloat16(lo[k]);
      cv[k + 4] = __float2bfloat16(hi[k]);
    }
    *(bf16x8*)(oa + i) = *(const bf16x8*)cv;
  }
  for (size_t i = base; i < nb; i += stride) {
    f32x4 lo = *(const f32x4*)(b + i);
    f32x4 hi = *(const f32x4*)(b + i + 4);
    bf16 cv[8];
#pragma unroll
    for (int k = 0; k < 4; ++k) {
      cv[k]     = __float2bfloat16(lo[k]);
      cv[k + 4] = __float2bfloat16(hi[k]);
    }
    *(bf16x8*)(ob + i) = *(const bf16x8*)cv;
  }
}

// ------------- 2-phase double-buffered bf16 grouped GEMM --------------------
__device__ __forceinline__ void stage_tile(bf16* AsBuf, bf16* BsBuf,
    const bf16* __restrict__ A, const bf16* __restrict__ Bexp,
    int m0, int n0, int kt, int K, int wave, int rA, int sA) {
  // tile = 128x32 bf16 = 8KB = 8 chunks of 1024B (16 rows). Wave w stages
  // chunks {2w,2w+1} of A and B; lane l -> row l>>2, colseg (l&3)*8 (=l*16B).
#pragma unroll
  for (int c = 0; c < 2; ++c) {
    const int chunk = wave * 2 + c;
    const int row = chunk * 16 + rA;
    async16(&AsBuf[chunk * 16 * BK], A    + (size_t)(m0 + row) * K + kt + sA);
    async16(&BsBuf[chunk * 16 * BK], Bexp + (size_t)(n0 + row) * K + kt + sA);
  }
}

__device__ __forceinline__ void mma_tile(const bf16* As, const bf16* Bs,
    int wrow, int wcol, int frow, int fk, f32x4 (&acc)[4][4]) {
  bf16x8 af[4], bfr[4];
#pragma unroll
  for (int i = 0; i < 4; ++i)
    af[i] = *(const bf16x8*)&As[(wrow + i * 16 + frow) * BK + fk];
#pragma unroll
  for (int j = 0; j < 4; ++j)
    bfr[j] = *(const bf16x8*)&Bs[(wcol + j * 16 + frow) * BK + fk];
#pragma unroll
  for (int i = 0; i < 4; ++i)
#pragma unroll
    for (int j = 0; j < 4; ++j)
      acc[i][j] = __builtin_amdgcn_mfma_f32_16x16x32_bf16(af[i], bfr[j], acc[i][j], 0, 0, 0);
}

__global__ __launch_bounds__(256) void gemm_bt_bf16(
    const bf16* __restrict__ A,      // [M, K] row-major bf16
    const bf16* __restrict__ B,      // [E, N, K] row-major bf16 (B^T gemm)
    const float* __restrict__ bias,  // [E, N] fp32
    void* __restrict__ Cv,           // [M, N] output
    const int* __restrict__ counts,  // [E]
    int E, int N, int K, int c_is_bf16_gelu)
{
  __shared__ alignas(16) bf16 As[2][BM * BK];   // 2 x 8 KB
  __shared__ alignas(16) bf16 Bs[2][BN * BK];   // 2 x 8 KB

  const int tid  = threadIdx.x;
  const int lane = tid & 63;
  const int wave = tid >> 6;

  // T1: bijective XCD-aware block swizzle (m204). HW round-robins orig%8
  // across XCDs; relabel so each XCD owns a contiguous run of logical tiles
  // (same row-band -> A panel stays in that XCD's L2).
  const int gx   = gridDim.x;
  const int nwg  = gx * gridDim.y;
  const int orig = blockIdx.y * gx + blockIdx.x;
  const int qq = nwg >> 3, rr = nwg & 7;
  const int xcd = orig & 7, lo = orig >> 3;
  const int wgid = (xcd < rr ? xcd * (qq + 1) : rr * (qq + 1) + (xcd - rr) * qq) + lo;
  const int m0 = (wgid / gx) * BM;
  const int n0 = (wgid % gx) * BN;

  // expert id for this row tile; block-uniform (no divergent barriers)
  int eid = 0;
  {
    long long cum = 0;
    for (int e = 0; e < E; ++e) { cum += counts[e]; if (m0 >= cum) eid = e + 1; }
  }

  const int wrow = (wave >> 1) * 64;   // wave tile 64x64 within 128x128
  const int wcol = (wave & 1) * 64;

  f32x4 acc[4][4] = {};

  if (eid < E) {
    const bf16* Bexp = B + (size_t)eid * (size_t)N * (size_t)K;
    const int rA = lane >> 2;          // row within 16-row chunk
    const int sA = (lane & 3) * 8;     // col segment (bf16 elems)
    const int frow = lane & 15;        // A/B frag row (m or n within 16)
    const int fk   = (lane >> 4) * 8;  // A/B frag k-offset (quad*8)
    const int nt = K / BK;

    // prologue: stage tile 0 into buf 0 (4 outstanding loads per lane)
    stage_tile(As[0], Bs[0], A, Bexp, m0, n0, 0, K, wave, rA, sA);

    int cur = 0;
    for (int t = 0; t < nt - 1; ++t) {
      // issue next tile's loads first -- they stay in flight across the
      // barrier (counted vmcnt, T4). 4 new loads per lane.
      stage_tile(As[cur ^ 1], Bs[cur ^ 1], A, Bexp, m0, n0, (t + 1) * BK,
                 K, wave, rA, sA);
      // wait only for the 4 OLDEST loads (current tile); next tile's 4 may
      // still be in flight.
      asm volatile("s_waitcnt vmcnt(4)" ::: "memory");
      __builtin_amdgcn_s_barrier();   // all waves' cur-tile stores visible
      mma_tile(As[cur], Bs[cur], wrow, wcol, frow, fk, acc);
      __builtin_amdgcn_s_barrier();   // all reads of buf[cur] done before
                                      // iter t+1 overwrites it
      cur ^= 1;
    }
    // epilogue: last tile, drain fully
    asm volatile("s_waitcnt vmcnt(0)" ::: "memory");
    __builtin_amdgcn_s_barrier();
    mma_tile(As[cur], Bs[cur], wrow, wcol, frow, fk, acc);
  }

  // epilogue: C/D layout col=lane&15, row=(lane>>4)*4+reg (m89-verified)
  const int crow = (lane >> 4) * 4;
  const int ccol = lane & 15;
  const int do_gelu = c_is_bf16_gelu;

  if (eid < E) {
    float bv[4];
#pragma unroll
    for (int j = 0; j < 4; ++j)
      bv[j] = bias[(size_t)eid * N + n0 + wcol + j * 16 + ccol];
#pragma unroll
    for (int i = 0; i < 4; ++i) {
#pragma unroll
      for (int r = 0; r < 4; ++r) {
        size_t grow = (size_t)(m0 + wrow + i * 16 + crow + r);
#pragma unroll
        for (int j = 0; j < 4; ++j) {
          float v = acc[i][j][r] + bv[j];
          size_t idx = grow * N + n0 + wcol + j * 16 + ccol;
          if (do_gelu) ((bf16*)Cv)[idx] = __float2bfloat16(gelu_f(v));
          else         ((float*)Cv)[idx] = v;
        }
      }
    }
  } else {
    // tokens beyond cumsum(counts): write zeros
#pragma unroll
    for (int i = 0; i < 4; ++i) {
#pragma unroll
      for (int r = 0; r < 4; ++r) {
        size_t grow = (size_t)(m0 + wrow + i * 16 + crow + r);
#pragma unroll
        for (int j = 0; j < 4; ++j) {
          size_t idx = grow * N + n0 + wcol + j * 16 + ccol;
          if (do_gelu) ((bf16*)Cv)[idx] = __float2bfloat16(0.0f);
          else         ((float*)Cv)[idx] = 0.0f;
        }
      }
    }
  }
}

// ---------------- fallback path (proven reg-staged kernel) ------------------
__device__ __forceinline__ void stage_f32(const float* g, bf16* lds,
                                          int srow, int seg, int ldg) {
#pragma unroll
  for (int h = 0; h < 2; ++h) {
    const float* p = g + (size_t)(srow + h * 64) * ldg + seg;
    f32x4 lo = *(const f32x4*)(p);
    f32x4 hi = *(const f32x4*)(p + 4);
    bf16 cv[8];
#pragma unroll
    for (int i = 0; i < 4; ++i) {
      cv[i]     = __float2bfloat16(lo[i]);
      cv[i + 4] = __float2bfloat16(hi[i]);
    }
    *(bf16x8*)&lds[(srow + h * 64) * BK + seg] = *(const bf16x8*)cv;
  }
}

__device__ __forceinline__ void stage_bf16f(const bf16* g, bf16* lds,
                                            int srow, int seg, int ldg) {
#pragma unroll
  for (int h = 0; h < 2; ++h) {
    const bf16* p = g + (size_t)(srow + h * 64) * ldg + seg;
    *(bf16x8*)&lds[(srow + h * 64) * BK + seg] = *(const bf16x8*)p;
  }
}

template <bool AF32>
__global__ __launch_bounds__(256) void grouped_gemm_bt(
    const void* __restrict__ Av, const float* __restrict__ B,
    const float* __restrict__ bias, void* __restrict__ Cv,
    const int* __restrict__ counts, int E, int N, int K, int c_is_bf16_gelu)
{
  __shared__ alignas(16) bf16 As[BM * BK];
  __shared__ alignas(16) bf16 Bs[BN * BK];

  const int tid  = threadIdx.x;
  const int lane = tid & 63;
  const int wave = tid >> 6;
  const int m0 = blockIdx.y * BM;
  const int n0 = blockIdx.x * BN;

  int eid = 0;
  {
    long long cum = 0;
    for (int e = 0; e < E; ++e) { cum += counts[e]; if (m0 >= cum) eid = e + 1; }
  }

  const int wrow = (wave >> 1) * 64;
  const int wcol = (wave & 1) * 64;

  f32x4 acc[4][4] = {};

  if (eid < E) {
    const float* Bexp = B + (size_t)eid * (size_t)N * (size_t)K;
    const int srow = tid >> 2;
    const int seg  = (tid & 3) * 8;
    const int frow = lane & 15;
    const int fk   = (lane >> 4) * 8;

    for (int kt = 0; kt < K; kt += BK) {
      if (AF32)
        stage_f32((const float*)Av + (size_t)(m0 + srow) * K + kt - (size_t)srow * K,
                  As, srow, seg, K);
      else
        stage_bf16f((const bf16*)Av + (size_t)(m0 + srow) * K + kt - (size_t)srow * K,
                    As, srow, seg, K);
      stage_f32(Bexp + (size_t)(n0 + srow) * K + kt - (size_t)srow * K,
                Bs, srow, seg, K);
      __syncthreads();

      bf16x8 af[4], bfr[4];
#pragma unroll
      for (int i = 0; i < 4; ++i)
        af[i] = *(const bf16x8*)&As[(wrow + i * 16 + frow) * BK + fk];
#pragma unroll
      for (int j = 0; j < 4; ++j)
        bfr[j] = *(const bf16x8*)&Bs[(wcol + j * 16 + frow) * BK + fk];

#pragma unroll
      for (int i = 0; i < 4; ++i)
#pragma unroll
        for (int j = 0; j < 4; ++j)
          acc[i][j] = __builtin_amdgcn_mfma_f32_16x16x32_bf16(af[i], bfr[j], acc[i][j], 0, 0, 0);

      __syncthreads();
    }
  }

  const int crow = (lane >> 4) * 4;
  const int ccol = lane & 15;
  const int do_gelu = c_is_bf16_gelu;

  if (eid < E) {
    float bv[4];
#pragma unroll
    for (int j = 0; j < 4; ++j)
      bv[j] = bias[(size_t)eid * N + n0 + wcol + j * 16 + ccol];
#pragma unroll
    for (int i = 0; i < 4; ++i) {
#pragma unroll
      for (int r = 0; r < 4; ++r) {
        size_t grow = (size_t)(m0 + wrow + i * 16 + crow + r);
#pragma unroll
        for (int j = 0; j < 4; ++j) {
          float v = acc[i][j][r] + bv[j];
          size_t idx = grow * N + n0 + wcol + j * 16 + ccol;
          if (do_gelu) ((bf16*)Cv)[idx] = __float2bfloat16(gelu_f(v));
          else         ((float*)Cv)[idx] = v;
        }
      }
    }
  } else {
#pragma unroll
    for (int i = 0; i < 4; ++i) {
#pragma unroll
      for (int r = 0; r < 4; ++r) {
        size_t grow = (size_t)(m0 + wrow + i * 16 + crow + r);
#pragma unroll
        for (int j = 0; j < 4; ++j) {
          size_t idx = grow * N + n0 + wcol + j * 16 + ccol;
          if (do_gelu) ((bf16*)Cv)[idx] = __float2bfloat16(0.0f);
          else         ((float*)Cv)[idx] = 0.0f;
        }
      }
    }
  }
}

extern "C" void kernel_launch(void* const* d_in, const int* in_sizes, int n_in,
                              void* d_out, int out_size, void* d_ws, size_t ws_size,
                              hipStream_t stream) {
  const float* inp = (const float*)d_in[0];  // [T, D] fp32
  const float* w1  = (const float*)d_in[1];  // [E, H, D] fp32
  const float* b1  = (const float*)d_in[2];  // [E, H] fp32
  const float* w2  = (const float*)d_in[3];  // [E, D, H] fp32
  const float* b2  = (const float*)d_in[4];  // [E, D] fp32
  const int* cnt   = (const int*)d_in[5];    // [E] int32
  float* out = (float*)d_out;                // [T, D] fp32

  const int E = in_sizes[5];
  const int H = in_sizes[2] / E;             // b1 = E*H
  const int D = in_sizes[4] / E;             // b2 = E*D
  const int T = in_sizes[0] / D;             // inp = T*D

  const size_t szH = (size_t)T * H * sizeof(bf16);             // h buffer
  const size_t szX = (size_t)T * D * sizeof(bf16);             // x bf16
  const size_t szW = (size_t)E * (size_t)H * D * sizeof(bf16); // w slot (shared)

  dim3 blk(256);

  if (ws_size >= szH + szX + szW) {
    // fast path: bf16 pre-converts (fused: x+w1, then w2 reusing slot),
    // 2-phase global_load_lds GEMMs.
    bf16* h  = (bf16*)d_ws;                            // [T, H]
    bf16* xb = (bf16*)((char*)d_ws + szH);             // [T, D]
    bf16* wb = (bf16*)((char*)d_ws + szH + szX);       // w1 then w2

    const size_t nX = (size_t)T * D;
    const size_t nW = (size_t)E * (size_t)H * D;

    f32_to_bf16_2<<<dim3(2048), blk, 0, stream>>>(inp, xb, nX, w1, wb, nW);
    gemm_bt_bf16<<<dim3(H / BN, T / BM), blk, 0, stream>>>(
        xb, wb, b1, h, cnt, E, H, D, 1);
    // stream-serial: GEMM1 finished reading wb before w2 overwrite
    f32_to_bf16_2<<<dim3(2048), blk, 0, stream>>>(w2, wb, nW, nullptr, nullptr, 0);
    gemm_bt_bf16<<<dim3(D / BN, T / BM), blk, 0, stream>>>(
        h, wb, b2, out, cnt, E, D, H, 0);
  } else {
    // fallback: proven reg-staged kernel
    bf16* h = (bf16*)d_ws;                             // [T, H]
    grouped_gemm_bt<true><<<dim3(H / BN, T / BM), blk, 0, stream>>>(inp, w1, b1, h, cnt, E, H, D, 1);
    grouped_gemm_bt<false><<<dim3(D / BN, T / BM), blk, 0, stream>>>(h, w2, b2, out, cnt, E, D, H, 0);
  }
}